// Round 15
// baseline (451.966 us; speedup 1.0000x reference)
//
#include <hip/hip_runtime.h>

// 2-layer LSTM (H=50) + linear head — MFMA v10: merged-wave (L0+L1 in one wave).
//
// v9 (373us): 8 waves, L0-wave + L1-wave per SIMD, barrier-lockstepped ->
// ~750 cyc/step of convoy-exposed latency (both waves in the same phase).
// v10: merge the L0 and L1 roles into ONE wave (block = 4 waves, 1/SIMD,
// __launch_bounds__(256,1) so ~220 unified regs are legal, no spill):
//   - L0(t) and L1(t-1) are mutually independent within a step (both read
//     only hc[p]) -> compiler statically interleaves 24 MFMA + 8 EW bodies:
//     L0's EW hides under L1's MFMA chain, 8 trans bodies pipeline the
//     trans unit, a0/a1 (h0) read once instead of twice (-2 ds_read/step).
//   - L1 MFMA as two independent 2-chains + add (halves serial latency).
//   - barrier population 8 -> 4 waves.
// Everything else = v9: MB=16, grid=256 (1 block/CU), hc[2] double buffer
// ([h0 0..49 | x 50,51 | 1.0@52 | pad | h1 @64..113 | pad]), prescaled
// weights (i,f,o: -log2e; g: +2log2e), fused-rcp EW (5 exp2 + 3 rcp),
// c-state in 2log2e domain, one __syncthreads per step.
//
// Decision rule (pre-committed): dur >= ~380us with WRITE_SIZE ~16KB ->
// single-wave stalls == convoy stalls -> v9 is the floor; declare roofline.

typedef _Float16 f16;
typedef f16  f16x8 __attribute__((ext_vector_type(8)));
typedef float f32x4 __attribute__((ext_vector_type(4)));
typedef unsigned short u16;
typedef unsigned int   u32;

#define TT   512
#define MB   16     // batches per block (= MFMA M)
#define KP   136    // hc row length in f16 (128 + 8 pad)
#define XTP  513    // xpack row pad
#define BLK  256    // 4 waves, one per SIMD

#define EXP2(v) __builtin_amdgcn_exp2f(v)
__device__ __forceinline__ float rcp_(float v) { return __builtin_amdgcn_rcpf(v); }

#define L2E  1.4426950408889634f
#define L2E2 2.8853900817779268f

// Weight element for B-fragment position (layer, gate g, out-unit u, k),
// pre-scaled: gates i,f,o (g=0,1,3) by -log2e; gate g (g=2) by +2*log2e.
// K layout: L0 [Whh0 0..49 | Wih0 50,51 | b0 @52]; L1 [Wih1 0..49 | b1 @52 |
// Whh1 @64..113]; all other k = 0.
__device__ __forceinline__ float welem(int layer, int g, int u, int k,
        const float* __restrict__ Wih0, const float* __restrict__ Whh0,
        const float* __restrict__ b0,
        const float* __restrict__ Wih1, const float* __restrict__ Whh1,
        const float* __restrict__ b1) {
    if (u >= 50) return 0.0f;
    const float s = (g == 2) ? L2E2 : -L2E;
    const int row = g * 50 + u;           // PyTorch gate order i,f,g,o
    if (layer == 0) {
        if (k < 50)  return s * Whh0[row * 50 + k];
        if (k < 52)  return s * Wih0[row * 2 + (k - 50)];
        if (k == 52) return s * b0[row];
        return 0.0f;
    } else {
        if (k < 50)             return s * Wih1[row * 50 + k];
        if (k == 52)            return s * b1[row];
        if (k >= 64 && k < 114) return s * Whh1[row * 50 + (k - 64)];
        return 0.0f;
    }
}

// Fused elementwise: pre-scaled gate sums, cell state kept in 2log2e domain.
// i*g' = L2E2*(eG-1)*rcp((1+eI)(1+eG)); h = (eC-1)*rcp((1+eO)(eC+1)).
#define EWFUSED(YI, YF, YG, YO, CS, HOUT)                                     \
    {                                                                         \
        const float eI = EXP2(YI);                                            \
        const float eF = EXP2(YF);                                            \
        const float eG = EXP2(YG);                                            \
        const float eO = EXP2(YO);                                            \
        const float fg  = rcp_(1.0f + eF);                                    \
        const float num = fmaf(L2E2, eG, -L2E2);                              \
        const float igg = num * rcp_((1.0f + eI) * (1.0f + eG));              \
        CS = fmaf(fg, CS, igg);                                               \
        const float cc = fminf(fmaxf(CS, -80.0f), 80.0f);                     \
        const float eC = EXP2(cc);                                            \
        HOUT = (eC - 1.0f) * rcp_((1.0f + eO) * (eC + 1.0f));                 \
    }

extern "C" __global__ void __launch_bounds__(BLK, 1)
lstm2_v10(const float* __restrict__ x,
          const float* __restrict__ W_ih0, const float* __restrict__ W_hh0,
          const float* __restrict__ b0,
          const float* __restrict__ W_ih1, const float* __restrict__ W_hh1,
          const float* __restrict__ b1,
          const float* __restrict__ W_fc,  const float* __restrict__ b_fc,
          float* __restrict__ out)
{
    __shared__ __align__(16) u16 hc[2][MB][KP];   // 8.7 KB double-buffered state
    __shared__ u32   xpack[MB][XTP];              // 32.8 KB packed f16 x pairs
    __shared__ float hfin[MB][52];                // final h1 (fp32) for the head

    const int tid   = threadIdx.x;
    const int lane  = tid & 63;
    const int wid   = tid >> 6;        // 0..3 = unit-block, handles BOTH layers
    const int ub    = wid;
    const int col   = lane & 15;       // A-row (batch) / B-col (unit) / D-col
    const int kg    = lane >> 4;       // k-octet / D-row group
    const int bbase = blockIdx.x * MB;

    // ---- stage x -> packed f16 pairs in LDS (coalesced float2 loads) ----
    for (int idx = tid; idx < MB * TT; idx += BLK) {
        const int b = idx >> 9, t = idx & (TT - 1);
        const float2 v = *reinterpret_cast<const float2*>(
            x + ((size_t)(bbase + b) * TT + t) * 2);
        xpack[b][t] = (u32)__builtin_bit_cast(u16, (f16)v.x)
                    | ((u32)__builtin_bit_cast(u16, (f16)v.y) << 16);
    }
    // ---- zero hc (both buffers; pads stay 0 forever) ----
    {
        u32* hcU = reinterpret_cast<u32*>(&hc[0][0][0]);
        for (int i = tid; i < 2 * MB * KP / 2; i += BLK) hcU[i] = 0;
    }
    __syncthreads();
    // bias slot (k=52) = f16 1.0 in both buffers; x(0) into buffer 0
    if (tid < 32) hc[tid >> 4][tid & 15][52] = (u16)0x3C00;
    else if (tid < 48)
        *reinterpret_cast<u32*>(&hc[0][tid - 32][50]) = xpack[tid - 32][0];

    // ---- static weight B-fragments for BOTH layers (constant loops -> regs) ----
    // B map: lane l, elem e <-> B[k = kf*32 + 8*kg + e][n = col]; identical
    // (lane,e)->k map as the A reads -> in-octet permutations cancel.
    const int u = 16 * ub + col;
    f16x8 bf0[4][2];   // L0 [gate][kf], K=64
    f16x8 bf1[4][4];   // L1 [gate][kf], K=128
#pragma unroll
    for (int g = 0; g < 4; ++g) {
#pragma unroll
        for (int kf = 0; kf < 2; ++kf) {
            f16x8 v;
#pragma unroll
            for (int e = 0; e < 8; ++e)
                v[e] = (f16)welem(0, g, u, kf * 32 + 8 * kg + e,
                                  W_ih0, W_hh0, b0, W_ih1, W_hh1, b1);
            bf0[g][kf] = v;
        }
#pragma unroll
        for (int kf = 0; kf < 4; ++kf) {
            f16x8 v;
#pragma unroll
            for (int e = 0; e < 8; ++e)
                v[e] = (f16)welem(1, g, u, kf * 32 + 8 * kg + e,
                                  W_ih0, W_hh0, b0, W_ih1, W_hh1, b1);
            bf1[g][kf] = v;
        }
    }

    float cst0[4] = {0.f, 0.f, 0.f, 0.f};   // L0 cell state (L2E2 domain)
    float cst1[4] = {0.f, 0.f, 0.f, 0.f};   // L1 cell state
    const f32x4 z = {0.f, 0.f, 0.f, 0.f};
    __syncthreads();

    for (int it = 0; it <= TT; ++it) {
        const int p = it & 1, q = p ^ 1;

        // ---- A-fragments: h0(it-1) once (shared by L0 and L1), h1(it-2) ----
        const f16x8 a0 = *reinterpret_cast<const f16x8*>(&hc[p][col][8 * kg]);
        const f16x8 a1 = *reinterpret_cast<const f16x8*>(&hc[p][col][32 + 8 * kg]);
        const f16x8 a2 = *reinterpret_cast<const f16x8*>(&hc[p][col][64 + 8 * kg]);
        const f16x8 a3 = *reinterpret_cast<const f16x8*>(&hc[p][col][96 + 8 * kg]);

        f32x4 acc0[4], acc1[4];
        const bool doL0 = (it < TT), doL1 = (it >= 1);

        __builtin_amdgcn_s_setprio(1);
        if (doL0) {
#pragma unroll
            for (int g = 0; g < 4; ++g) {
                f32x4 c  = __builtin_amdgcn_mfma_f32_16x16x32_f16(a0, bf0[g][0], z, 0, 0, 0);
                acc0[g]  = __builtin_amdgcn_mfma_f32_16x16x32_f16(a1, bf0[g][1], c, 0, 0, 0);
            }
        }
        if (doL1) {
#pragma unroll
            for (int g = 0; g < 4; ++g) {
                // two independent 2-chains + add: halves serial MFMA latency
                f32x4 cA = __builtin_amdgcn_mfma_f32_16x16x32_f16(a0, bf1[g][0], z, 0, 0, 0);
                f32x4 cB = __builtin_amdgcn_mfma_f32_16x16x32_f16(a2, bf1[g][2], z, 0, 0, 0);
                cA = __builtin_amdgcn_mfma_f32_16x16x32_f16(a1, bf1[g][1], cA, 0, 0, 0);
                cB = __builtin_amdgcn_mfma_f32_16x16x32_f16(a3, bf1[g][3], cB, 0, 0, 0);
                acc1[g] = cA + cB;
            }
        }
        __builtin_amdgcn_s_setprio(0);

        // ---- EW: 8 independent bodies (4 L0 + 4 L1) pipeline the trans unit ----
        // D map (HW-verified): D[row = 4*kg + r][col]; row=batch, col=unit.
        if (u < 50) {
            if (doL0) {
#pragma unroll
                for (int r = 0; r < 4; ++r) {
                    float hv;
                    EWFUSED(acc0[0][r], acc0[1][r], acc0[2][r], acc0[3][r], cst0[r], hv);
                    hc[q][4 * kg + r][u] = __builtin_bit_cast(u16, (f16)hv);
                }
            }
            if (doL1) {
#pragma unroll
                for (int r = 0; r < 4; ++r) {
                    float hv;
                    EWFUSED(acc1[0][r], acc1[1][r], acc1[2][r], acc1[3][r], cst1[r], hv);
                    hc[q][4 * kg + r][64 + u] = __builtin_bit_cast(u16, (f16)hv);
                    if (it == TT) hfin[4 * kg + r][u] = hv;
                }
            }
        }
        // next step's x into hc[q] slots 50,51 (one u32 per batch, wave 0)
        if (wid == 0 && lane < MB && (it + 1) < TT)
            *reinterpret_cast<u32*>(&hc[q][lane][50]) = xpack[lane][it + 1];

        __syncthreads();
    }

    // ===== final linear head on fp32 h1[T-1] =====
    if (tid < MB) {
        float d = b_fc[0];
#pragma unroll
        for (int uu = 0; uu < 50; ++uu) d = fmaf(W_fc[uu], hfin[tid][uu], d);
        out[bbase + tid] = d;
    }
}

extern "C" void kernel_launch(void* const* d_in, const int* in_sizes, int n_in,
                              void* d_out, int out_size, void* d_ws, size_t ws_size,
                              hipStream_t stream) {
    const float* x     = (const float*)d_in[0];
    const float* W_ih0 = (const float*)d_in[1];
    const float* W_hh0 = (const float*)d_in[2];
    const float* b0    = (const float*)d_in[3];
    const float* W_ih1 = (const float*)d_in[4];
    const float* W_hh1 = (const float*)d_in[5];
    const float* b1    = (const float*)d_in[6];
    const float* W_fc  = (const float*)d_in[7];
    const float* b_fc  = (const float*)d_in[8];
    float* out = (float*)d_out;

    const int B = in_sizes[0] / (TT * 2);    // 4096
    dim3 grid(B / MB), block(BLK);           // 256 blocks = 1 per CU
    hipLaunchKernelGGL(lstm2_v10, grid, block, 0, stream,
                       x, W_ih0, W_hh0, b0, W_ih1, W_hh1, b1, W_fc, b_fc, out);
}

// Round 16
// 373.286 us; speedup vs baseline: 1.2108x; 1.2108x over previous
//
#include <hip/hip_runtime.h>

// 2-layer LSTM (H=50) + linear head — MFMA v9 (FINAL, 373us measured r14).
//
// Best of 15 rounds. Structure: 8 waves (waves 0-3 L0, 4-7 L1, L1 lags one
// step), MB=16 batches/block, grid=256 (1 block/CU), hc[2] double buffer with
// x at k=50,51 and bias-slot 1.0 at k=52 (bias folded into K, PRESCALED),
// per-step x copy by wave 0, one __syncthreads per step, static B-fragments
// in registers, s_setprio around MFMA.
// Fused-rcp elementwise (8 trans/body = algebraic floor): weights prescaled
// (i,f,o by -log2e; g by +2log2e), cell state kept in the 2log2e domain.
//
// Roofline note: period ~1750 cyc/step vs ~1000 cyc/SIMD/step issue
// (VALUBusy 57%); trans floor ~450 cyc. Occupancy axis exhausted both ways
// (1 wave/SIMD = 452us exposed latency; 3-4 waves = 444-1184us issue/spill),
// three sync protocols equivalent (barrier/async-atomic/flags), EW algebra
// at floor. This is the practical floor of this decomposition on MI355X.

typedef _Float16 f16;
typedef f16  f16x8 __attribute__((ext_vector_type(8)));
typedef float f32x4 __attribute__((ext_vector_type(4)));
typedef unsigned short u16;
typedef unsigned int   u32;

#define TT   512
#define MB   16     // batches per block (= MFMA M)
#define KP   136    // hc row length in f16 (128 + 8 pad)
#define XTP  513    // xpack row pad
#define BLK  512    // 8 waves

#define EXP2(v) __builtin_amdgcn_exp2f(v)
__device__ __forceinline__ float rcp_(float v) { return __builtin_amdgcn_rcpf(v); }

#define L2E  1.4426950408889634f
#define L2E2 2.8853900817779268f

// Weight element for B-fragment position (layer, gate g, out-unit u, k),
// pre-scaled: gates i,f,o (g=0,1,3) by -log2e; gate g (g=2) by +2*log2e.
// K layout: L0 [Whh0 0..49 | Wih0 50,51 | b0 @52]; L1 [Wih1 0..49 | b1 @52 |
// Whh1 @64..113]; all other k = 0.
__device__ __forceinline__ float welem(int layer, int g, int u, int k,
        const float* __restrict__ Wih0, const float* __restrict__ Whh0,
        const float* __restrict__ b0,
        const float* __restrict__ Wih1, const float* __restrict__ Whh1,
        const float* __restrict__ b1) {
    if (u >= 50) return 0.0f;
    const float s = (g == 2) ? L2E2 : -L2E;
    const int row = g * 50 + u;           // PyTorch gate order i,f,g,o
    if (layer == 0) {
        if (k < 50)  return s * Whh0[row * 50 + k];
        if (k < 52)  return s * Wih0[row * 2 + (k - 50)];
        if (k == 52) return s * b0[row];
        return 0.0f;
    } else {
        if (k < 50)             return s * Wih1[row * 50 + k];
        if (k == 52)            return s * b1[row];
        if (k >= 64 && k < 114) return s * Whh1[row * 50 + (k - 64)];
        return 0.0f;
    }
}

// Fused elementwise: pre-scaled gate sums, cell state kept in 2log2e domain.
// i*g' = L2E2*(eG-1)*rcp((1+eI)(1+eG)); h = (eC-1)*rcp((1+eO)(eC+1)).
#define EWFUSED(YI, YF, YG, YO, CS, HOUT)                                     \
    {                                                                         \
        const float eI = EXP2(YI);                                            \
        const float eF = EXP2(YF);                                            \
        const float eG = EXP2(YG);                                            \
        const float eO = EXP2(YO);                                            \
        const float fg  = rcp_(1.0f + eF);                                    \
        const float num = fmaf(L2E2, eG, -L2E2);                              \
        const float igg = num * rcp_((1.0f + eI) * (1.0f + eG));              \
        CS = fmaf(fg, CS, igg);                                               \
        const float cc = fminf(fmaxf(CS, -80.0f), 80.0f);                     \
        const float eC = EXP2(cc);                                            \
        HOUT = (eC - 1.0f) * rcp_((1.0f + eO) * (eC + 1.0f));                 \
    }

extern "C" __global__ void __launch_bounds__(BLK, 2)
lstm2_v9(const float* __restrict__ x,
         const float* __restrict__ W_ih0, const float* __restrict__ W_hh0,
         const float* __restrict__ b0,
         const float* __restrict__ W_ih1, const float* __restrict__ W_hh1,
         const float* __restrict__ b1,
         const float* __restrict__ W_fc,  const float* __restrict__ b_fc,
         float* __restrict__ out)
{
    __shared__ __align__(16) u16 hc[2][MB][KP];   // 8.7 KB double-buffered state
    __shared__ u32   xpack[MB][XTP];              // 32.8 KB packed f16 x pairs
    __shared__ float hfin[MB][52];                // final h1 (fp32) for the head

    const int tid   = threadIdx.x;
    const int lane  = tid & 63;
    const int wid   = tid >> 6;        // 0..7
    const int layer = wid >> 2;        // waves 0-3: L0, waves 4-7: L1
    const int ub    = wid & 3;         // unit-block (16 units)
    const int col   = lane & 15;       // A-row (batch) / B-col (unit) / D-col
    const int kg    = lane >> 4;       // k-octet / D-row group
    const int bbase = blockIdx.x * MB;

    // ---- stage x -> packed f16 pairs in LDS (coalesced float2 loads) ----
    for (int idx = tid; idx < MB * TT; idx += BLK) {
        const int b = idx >> 9, t = idx & (TT - 1);
        const float2 v = *reinterpret_cast<const float2*>(
            x + ((size_t)(bbase + b) * TT + t) * 2);
        xpack[b][t] = (u32)__builtin_bit_cast(u16, (f16)v.x)
                    | ((u32)__builtin_bit_cast(u16, (f16)v.y) << 16);
    }
    // ---- zero hc (both buffers; pads stay 0 forever) ----
    {
        u32* hcU = reinterpret_cast<u32*>(&hc[0][0][0]);
        for (int i = tid; i < 2 * MB * KP / 2; i += BLK) hcU[i] = 0;
    }
    __syncthreads();
    // bias slot (k=52) = f16 1.0 in both buffers; x(0) into buffer 0
    if (tid < 32) hc[tid >> 4][tid & 15][52] = (u16)0x3C00;
    else if (tid < 48)
        *reinterpret_cast<u32*>(&hc[0][tid - 32][50]) = xpack[tid - 32][0];

    // ---- static weight B-fragments (constant-bound loops -> registers) ----
    // B map: lane l, elem e <-> B[k = kf*32 + 8*kg + e][n = col]; identical
    // (lane,e)->k map as the A reads -> in-octet permutations cancel.
    const int u = 16 * ub + col;
    f16x8 bf[4][4];    // [gate][kf]; L0 kf=2,3 all-zero (unused on L0 path)
#pragma unroll
    for (int g = 0; g < 4; ++g) {
#pragma unroll
        for (int kf = 0; kf < 4; ++kf) {
            f16x8 v;
#pragma unroll
            for (int e = 0; e < 8; ++e)
                v[e] = (f16)welem(layer, g, u, kf * 32 + 8 * kg + e,
                                  W_ih0, W_hh0, b0, W_ih1, W_hh1, b1);
            bf[g][kf] = v;
        }
    }

    float cst[4] = {0.f, 0.f, 0.f, 0.f};   // cell state (L2E2 domain)
    const f32x4 z = {0.f, 0.f, 0.f, 0.f};
    __syncthreads();

    for (int it = 0; it <= TT; ++it) {
        const int p = it & 1, q = p ^ 1;
        f32x4 acc[4];

        if (layer == 0) {
            if (it < TT) {
                // A: lane l, elem e <-> hc[p][batch = col][k = kf*32 + 8*kg + e]
                const f16x8 a0 = *reinterpret_cast<const f16x8*>(&hc[p][col][8 * kg]);
                const f16x8 a1 = *reinterpret_cast<const f16x8*>(&hc[p][col][32 + 8 * kg]);
                __builtin_amdgcn_s_setprio(1);
#pragma unroll
                for (int g = 0; g < 4; ++g) {
                    f32x4 c = __builtin_amdgcn_mfma_f32_16x16x32_f16(a0, bf[g][0], z, 0, 0, 0);
                    acc[g]  = __builtin_amdgcn_mfma_f32_16x16x32_f16(a1, bf[g][1], c, 0, 0, 0);
                }
                __builtin_amdgcn_s_setprio(0);
                // D map (HW-verified): D[row = 4*kg + r][col]; row=batch, col=unit
                if (u < 50) {
#pragma unroll
                    for (int r = 0; r < 4; ++r) {
                        float hv;
                        EWFUSED(acc[0][r], acc[1][r], acc[2][r], acc[3][r], cst[r], hv);
                        hc[q][4 * kg + r][u] = __builtin_bit_cast(u16, (f16)hv);
                    }
                }
            }
        } else {
            if (it >= 1) {
                const f16x8 a0 = *reinterpret_cast<const f16x8*>(&hc[p][col][8 * kg]);
                const f16x8 a1 = *reinterpret_cast<const f16x8*>(&hc[p][col][32 + 8 * kg]);
                const f16x8 a2 = *reinterpret_cast<const f16x8*>(&hc[p][col][64 + 8 * kg]);
                const f16x8 a3 = *reinterpret_cast<const f16x8*>(&hc[p][col][96 + 8 * kg]);
                __builtin_amdgcn_s_setprio(1);
#pragma unroll
                for (int g = 0; g < 4; ++g) {
                    f32x4 c = __builtin_amdgcn_mfma_f32_16x16x32_f16(a0, bf[g][0], z, 0, 0, 0);
                    c       = __builtin_amdgcn_mfma_f32_16x16x32_f16(a1, bf[g][1], c, 0, 0, 0);
                    c       = __builtin_amdgcn_mfma_f32_16x16x32_f16(a2, bf[g][2], c, 0, 0, 0);
                    acc[g]  = __builtin_amdgcn_mfma_f32_16x16x32_f16(a3, bf[g][3], c, 0, 0, 0);
                }
                __builtin_amdgcn_s_setprio(0);
                if (u < 50) {
#pragma unroll
                    for (int r = 0; r < 4; ++r) {
                        float hv;
                        EWFUSED(acc[0][r], acc[1][r], acc[2][r], acc[3][r], cst[r], hv);
                        hc[q][4 * kg + r][64 + u] = __builtin_bit_cast(u16, (f16)hv);
                        if (it == TT) hfin[4 * kg + r][u] = hv;
                    }
                }
            }
        }
        // next step's x into hc[q] slots 50,51 (one u32 per batch, wave 0)
        if (wid == 0 && lane < MB && (it + 1) < TT)
            *reinterpret_cast<u32*>(&hc[q][lane][50]) = xpack[lane][it + 1];

        __syncthreads();
    }

    // ===== final linear head on fp32 h1[T-1] =====
    if (tid < MB) {
        float d = b_fc[0];
#pragma unroll
        for (int uu = 0; uu < 50; ++uu) d = fmaf(W_fc[uu], hfin[tid][uu], d);
        out[bbase + tid] = d;
    }
}

extern "C" void kernel_launch(void* const* d_in, const int* in_sizes, int n_in,
                              void* d_out, int out_size, void* d_ws, size_t ws_size,
                              hipStream_t stream) {
    const float* x     = (const float*)d_in[0];
    const float* W_ih0 = (const float*)d_in[1];
    const float* W_hh0 = (const float*)d_in[2];
    const float* b0    = (const float*)d_in[3];
    const float* W_ih1 = (const float*)d_in[4];
    const float* W_hh1 = (const float*)d_in[5];
    const float* b1    = (const float*)d_in[6];
    const float* W_fc  = (const float*)d_in[7];
    const float* b_fc  = (const float*)d_in[8];
    float* out = (float*)d_out;

    const int B = in_sizes[0] / (TT * 2);    // 4096
    dim3 grid(B / MB), block(BLK);           // 256 blocks = 1 per CU
    hipLaunchKernelGGL(lstm2_v9, grid, block, 0, stream,
                       x, W_ih0, W_hh0, b0, W_ih1, W_hh1, b1, W_fc, b_fc, out);
}